// Round 9
// baseline (408.291 us; speedup 1.0000x reference)
//
#include <hip/hip_runtime.h>
#include <hip/hip_bf16.h>
#include <math.h>

#define NE 200000
#define NN 25000

static constexpr float INV_SQRT3  = 0.5773502691896258f;
static constexpr float INV_SQRT2  = 0.7071067811865476f;
static constexpr float INV_SQRT8  = 0.3535533905932738f;
static constexpr float INV_SQRT24 = 0.2041241452319315f;

typedef __attribute__((ext_vector_type(8))) short bf16x8;
typedef __attribute__((ext_vector_type(4))) float f32x4;

union U16x8 { uint4 u; bf16x8 v; };

__device__ __forceinline__ unsigned f2bf1(float f) {
  unsigned u = __float_as_uint(f);
  return (u + 0x7FFFu + ((u >> 16) & 1u)) >> 16;
}
// native v_cvt_pk_bf16_f32 (RNE): a -> low 16, b -> high 16
__device__ __forceinline__ unsigned packbf(float a, float b) {
  union { __hip_bfloat162 h; unsigned u; } c;
  c.h = __float22bfloat162_rn(make_float2(a, b));
  return c.u;
}
__device__ __forceinline__ float bflo(unsigned u) { return __uint_as_float(u << 16); }
__device__ __forceinline__ float bfhi(unsigned u) { return __uint_as_float(u & 0xFFFF0000u); }

// ---------------- fused prep: W2 A-frags + W1 A-frags + node q's + dst histogram ----
__global__ __launch_bounds__(256) void prep_kernel(
    const float* __restrict__ kW1, const float* __restrict__ kW2,
    const float* __restrict__ vW1, const float* __restrict__ vW2,
    const float* __restrict__ node_attr,
    const float* __restrict__ Wq0, const float* __restrict__ Wq1,
    const float* __restrict__ Wd0, const float* __restrict__ Wd1,
    const int*   __restrict__ edge_index,
    unsigned short* __restrict__ afrag,
    unsigned short* __restrict__ afrag1,
    float* __restrict__ qd, float* __restrict__ qvd,
    int* __restrict__ hist)
{
  int t = blockIdx.x * blockDim.x + threadIdx.x;   // 40960 threads
  if (t < 4096) {
    int j    = t & 7;
    int lane = (t >> 3) & 63;
    int rt   = (t >> 9) & 3;
    int b    = (t >> 11) & 1;
    int quad = lane >> 4;
    int k    = quad * 8 + j;
    int jeff = k & 15;
    int r    = rt * 16 + (lane & 15);
    const float* W = b ? vW1 : kW1;
    afrag1[t] = (unsigned short)f2bf1(W[jeff * 64 + r]);
  }
  if (t < 40960) {
    int j    = t & 7;
    int lane = (t >> 3) & 63;
    int kk   = (t >> 9) & 1;
    int ot   = (t >> 10) & 1;
    int ci   = t >> 11;
    int b    = ci / 10;
    int rem  = ci - b * 10;
    int p    = rem >> 1;
    int hf   = rem & 1;
    int r    = kk * 32 + ((lane >> 4) << 3) + j;
    int o    = p * 64 + hf * 32 + ot * 16 + (lane & 15);
    const float* W = b ? vW2 : kW2;
    afrag[t] = (unsigned short)f2bf1(W[r * 320 + o]);
  }
#pragma unroll
  for (int i = 0; i < 5; ++i) {
    int e = t * 5 + i;
    if (e < NE) atomicAdd(&hist[edge_index[NE + e]], 1);
  }
  if (t < NN) {
    int n = t;
    float ns[8], nv[24];
#pragma unroll
    for (int i = 0; i < 8; ++i)  ns[i] = node_attr[n * 32 + i];
#pragma unroll
    for (int i = 0; i < 24; ++i) nv[i] = node_attr[n * 32 + 8 + i];
    float qs[8];
#pragma unroll
    for (int m = 0; m < 8; ++m) {
      float a = 0.f;
#pragma unroll
      for (int i = 0; i < 8; ++i) a = fmaf(ns[i], Wq0[i * 8 + m], a);
      qs[m] = a * INV_SQRT8;
    }
#pragma unroll
    for (int k = 0; k < 8; ++k) {
      float a = 0.f;
#pragma unroll
      for (int m = 0; m < 8; ++m) a = fmaf(qs[m], Wd0[m * 8 + k], a);
      qd[n * 8 + k] = a;
    }
    float qv[24];
#pragma unroll
    for (int k = 0; k < 8; ++k) {
#pragma unroll
      for (int c = 0; c < 3; ++c) {
        float a = 0.f;
#pragma unroll
        for (int m = 0; m < 8; ++m) a = fmaf(nv[m * 3 + c], Wq1[m * 8 + k], a);
        qv[k * 3 + c] = a * INV_SQRT8;
      }
    }
#pragma unroll
    for (int k = 0; k < 8; ++k) {
#pragma unroll
      for (int c = 0; c < 3; ++c) {
        float a = 0.f;
#pragma unroll
        for (int m = 0; m < 8; ++m) a = fmaf(qv[m * 3 + c], Wd1[m * 8 + k], a);
        qvd[n * 24 + k * 3 + c] = a;
      }
    }
  }
}

// ---------------- chunked shfl scan ----------------
__global__ __launch_bounds__(1024) void scan_kernel(
    const int* __restrict__ hist, int* __restrict__ off, int* __restrict__ cursor)
{
  __shared__ int wsum[16];
  const int tid  = threadIdx.x;
  const int lane = tid & 63;
  const int wv   = tid >> 6;
  const int base = tid * 25;
  int loc[25];
  int s = 0;
#pragma unroll
  for (int i = 0; i < 25; ++i) {
    int idx = base + i;
    int v = (idx < NN) ? hist[idx] : 0;
    loc[i] = s;
    s += v;
  }
  int incl = s;
#pragma unroll
  for (int d = 1; d < 64; d <<= 1) {
    int t = __shfl_up(incl, d, 64);
    if (lane >= d) incl += t;
  }
  int wexcl = incl - s;
  if (lane == 63) wsum[wv] = incl;
  __syncthreads();
  if (wv == 0 && lane < 16) {
    int v = wsum[lane];
    int inc2 = v;
#pragma unroll
    for (int d = 1; d < 16; d <<= 1) {
      int t = __shfl_up(inc2, d, 64);
      if (lane >= d) inc2 += t;
    }
    wsum[lane] = inc2 - v;
  }
  __syncthreads();
  int tbase = wsum[wv] + wexcl;
#pragma unroll
  for (int i = 0; i < 25; ++i) {
    int idx = base + i;
    if (idx < NN) { int e = tbase + loc[i]; off[idx] = e; cursor[idx] = e; }
  }
  if (tid == 1023) off[NN] = tbase + s;
}

// ---------------- main edge pass (all-MFMA, CSR output) ----------------
// R9: native pk-bf16 cvt (was ~8 inst/pair hand-rolled RNE), separable
// contraction (T/U accumulators, per-branch finals), A-frag software
// prefetch (next chunk loads issued before current chunk's contraction).
__global__ __launch_bounds__(256) void edge_kernel(
    const float* __restrict__ node_attr,
    const int*   __restrict__ edge_index,
    const float* __restrict__ edge_attr,
    const float* __restrict__ edge_sh,
    const unsigned short* __restrict__ afrag1,
    const unsigned short* __restrict__ afrag,
    const float* __restrict__ qd,   const float* __restrict__ qvd,
    int* __restrict__ cursor,
    float* __restrict__ exo, float* __restrict__ wout)
{
  __shared__ unsigned char smem[36864];
  const int tid  = threadIdx.x;
  const int lane = tid & 63;
  const int wave = tid >> 6;
  const int l15  = lane & 15;
  const int quad = lane >> 4;
  unsigned char* reg9k = smem + wave * 9216;   // per-wave region
  unsigned char* sea = reg9k;                  // 64 x 80 B (ea hi/lo frags)
  unsigned char* sh  = reg9k;                  // 64 x 144 B (h rows)
  unsigned char* swp = reg9k;                  // 64 x 80 B (w chunks)

  const int e = blockIdx.x * 256 + tid;
  const bool valid = (e < NE);
  const int el  = valid ? e : (NE - 1);
  const int src = edge_index[el];
  const int dst = edge_index[NE + el];

  int pos = 0;
  if (valid) pos = atomicAdd(&cursor[dst], 1);

  const float s0  = edge_sh[el * 4 + 0];
  const float s1x = edge_sh[el * 4 + 1];
  const float s1y = edge_sh[el * 4 + 2];
  const float s1z = edge_sh[el * 4 + 3];

  // ---- stage ea as bf16 hi + lo (error-compensated) into sea ----
  {
    float ea[16];
    const float4* ea4 = (const float4*)(edge_attr + (size_t)el * 16);
#pragma unroll
    for (int i = 0; i < 4; ++i) {
      float4 v = ea4[i];
      ea[4*i+0] = v.x; ea[4*i+1] = v.y; ea[4*i+2] = v.z; ea[4*i+3] = v.w;
    }
    unsigned char* myrow = sea + lane * 80;
    unsigned hi[8];
    float lo[16];
#pragma unroll
    for (int i = 0; i < 8; ++i) {
      unsigned pk = packbf(ea[2*i], ea[2*i+1]);
      hi[i] = pk;
      lo[2*i]   = ea[2*i]   - bflo(pk);
      lo[2*i+1] = ea[2*i+1] - bfhi(pk);
    }
    uint4 w0 = {hi[0], hi[1], hi[2], hi[3]};
    uint4 w1 = {hi[4], hi[5], hi[6], hi[7]};
    *(uint4*)(myrow)      = w0;
    *(uint4*)(myrow + 16) = w1;
    uint4 w2, w3;
    w2.x = packbf(lo[0], lo[1]);   w2.y = packbf(lo[2], lo[3]);
    w2.z = packbf(lo[4], lo[5]);   w2.w = packbf(lo[6], lo[7]);
    w3.x = packbf(lo[8], lo[9]);   w3.y = packbf(lo[10], lo[11]);
    w3.z = packbf(lo[12], lo[13]); w3.w = packbf(lo[14], lo[15]);
    *(uint4*)(myrow + 32) = w2;
    *(uint4*)(myrow + 48) = w3;
  }

  // ---- B1 fragments (ea) ----
  U16x8 B1[4];
#pragma unroll
  for (int et = 0; et < 4; ++et)
    B1[et].u = *(const uint4*)(sea + (et*16 + l15) * 80 + quad * 16);

  // ---- own-edge node values ----
  float xs[8], xv[8][3];
  {
    const float4* na4 = (const float4*)(node_attr + (size_t)src * 32);
    float tmp[32];
#pragma unroll
    for (int i = 0; i < 8; ++i) {
      float4 v = na4[i];
      tmp[4*i+0] = v.x; tmp[4*i+1] = v.y; tmp[4*i+2] = v.z; tmp[4*i+3] = v.w;
    }
#pragma unroll
    for (int m = 0; m < 8; ++m) xs[m] = tmp[m];
#pragma unroll
    for (int m = 0; m < 8; ++m) {
      xv[m][0] = tmp[8 + 3*m + 0];
      xv[m][1] = tmp[8 + 3*m + 1];
      xv[m][2] = tmp[8 + 3*m + 2];
    }
  }

  const uint4* AF  = (const uint4*)afrag;
  const uint4* AF1 = (const uint4*)afrag1;
  float ex = 0.f;

#pragma unroll 1
  for (int b = 0; b < 2; ++b) {
    // ---- layer-1: h = silu(ea @ W1 / 4) via 16 MFMA, bf16 h -> sh ----
#pragma unroll 1
    for (int rt = 0; rt < 4; ++rt) {
      U16x8 a1;
      a1.u = AF1[(b * 4 + rt) * 64 + lane];
#pragma unroll
      for (int et = 0; et < 4; ++et) {
        f32x4 c = {0.f, 0.f, 0.f, 0.f};
        c = __builtin_amdgcn_mfma_f32_16x16x32_bf16(a1.v, B1[et].v, c, 0, 0, 0);
        float hh[4];
#pragma unroll
        for (int i = 0; i < 4; ++i) {
          float x = c[i] * 0.25f;
          hh[i] = x / (1.f + __expf(-x));
        }
        uint2 pk;
        pk.x = packbf(hh[0], hh[1]);
        pk.y = packbf(hh[2], hh[3]);
        *(uint2*)(sh + (et*16 + l15) * 144 + (rt*16 + quad*4) * 2) = pk;
      }
    }

    // ---- B2 fragments (H) ----
    bf16x8 B[4][2];
#pragma unroll
    for (int et = 0; et < 4; ++et) {
#pragma unroll
      for (int kk = 0; kk < 2; ++kk) {
        U16x8 cv;
        cv.u = *(const uint4*)(sh + (et*16 + l15) * 144 + kk * 64 + quad * 16);
        B[et][kk] = cv.v;
      }
    }

    // separable accumulators
    float T0[8], T1[8], T3[8];
    float U2[8][3], U4[8][3];
#pragma unroll
    for (int n = 0; n < 8; ++n) {
      T0[n] = 0.f; T1[n] = 0.f; T3[n] = 0.f;
      U2[n][0] = 0.f; U2[n][1] = 0.f; U2[n][2] = 0.f;
      U4[n][0] = 0.f; U4[n][1] = 0.f; U4[n][2] = 0.f;
    }

    // ---- 10 chunks, unroll 1, A-frags software-prefetched ----
    U16x8 a0, a1_, a2, a3;
    {
      const int ci = b * 10;
      a0.u  = AF[(ci*4 + 0) * 64 + lane];
      a1_.u = AF[(ci*4 + 1) * 64 + lane];
      a2.u  = AF[(ci*4 + 2) * 64 + lane];
      a3.u  = AF[(ci*4 + 3) * 64 + lane];
    }
#pragma unroll 1
    for (int cc = 0; cc < 10; ++cc) {
      const int p  = cc >> 1;
      const int hf = cc & 1;
      // prefetch next chunk (clamped)
      U16x8 n0, n1, n2, n3;
      {
        const int cn = b * 10 + (cc < 9 ? cc + 1 : 9);
        n0.u = AF[(cn*4 + 0) * 64 + lane];
        n1.u = AF[(cn*4 + 1) * 64 + lane];
        n2.u = AF[(cn*4 + 2) * 64 + lane];
        n3.u = AF[(cn*4 + 3) * 64 + lane];
      }

#pragma unroll
      for (int et = 0; et < 4; ++et) {
        f32x4 c0 = {0.f, 0.f, 0.f, 0.f};
        f32x4 c1 = {0.f, 0.f, 0.f, 0.f};
        c0 = __builtin_amdgcn_mfma_f32_16x16x32_bf16(a0.v,  B[et][0], c0, 0, 0, 0);
        c0 = __builtin_amdgcn_mfma_f32_16x16x32_bf16(a1_.v, B[et][1], c0, 0, 0, 0);
        c1 = __builtin_amdgcn_mfma_f32_16x16x32_bf16(a2.v,  B[et][0], c1, 0, 0, 0);
        c1 = __builtin_amdgcn_mfma_f32_16x16x32_bf16(a3.v,  B[et][1], c1, 0, 0, 0);
        unsigned char* wrow = swp + (et*16 + l15) * 80;
        uint2 p0; p0.x = packbf(c0.x, c0.y); p0.y = packbf(c0.z, c0.w);
        uint2 p1; p1.x = packbf(c1.x, c1.y); p1.y = packbf(c1.z, c1.w);
        *(uint2*)(wrow + quad * 8)      = p0;
        *(uint2*)(wrow + 32 + quad * 8) = p1;
      }

      // consume w-chunk; separable contraction
      const uint4* wr = (const uint4*)(swp + (size_t)lane * 80);
#pragma unroll
      for (int h2 = 0; h2 < 2; ++h2) {
        uint4 qa = wr[h2 * 2], qb = wr[h2 * 2 + 1];
        float wvv[16];
        {
          unsigned qs_[8] = {qa.x,qa.y,qa.z,qa.w, qb.x,qb.y,qb.z,qb.w};
#pragma unroll
          for (int i = 0; i < 8; ++i) {
            wvv[2*i]   = bflo(qs_[i]);
            wvv[2*i+1] = bfhi(qs_[i]);
          }
        }
#pragma unroll
        for (int mm = 0; mm < 2; ++mm) {
          const int m = hf * 4 + h2 * 2 + mm;
          const float* wm = &wvv[mm * 8];
          if (p == 0) {
            const float g = xs[m];
#pragma unroll
            for (int n = 0; n < 8; ++n) T0[n] = fmaf(wm[n], g, T0[n]);
          } else if (p == 1) {
            const float g = xs[m];
#pragma unroll
            for (int n = 0; n < 8; ++n) T1[n] = fmaf(wm[n], g, T1[n]);
          } else if (p == 2) {
            const float g0 = xv[m][0], g1 = xv[m][1], g2 = xv[m][2];
#pragma unroll
            for (int n = 0; n < 8; ++n) {
              U2[n][0] = fmaf(wm[n], g0, U2[n][0]);
              U2[n][1] = fmaf(wm[n], g1, U2[n][1]);
              U2[n][2] = fmaf(wm[n], g2, U2[n][2]);
            }
          } else if (p == 3) {
            float dm = (xv[m][0]*s1x + xv[m][1]*s1y + xv[m][2]*s1z) * INV_SQRT3;
#pragma unroll
            for (int n = 0; n < 8; ++n) T3[n] = fmaf(wm[n], dm, T3[n]);
          } else {
            const float g0 = xv[m][0], g1 = xv[m][1], g2 = xv[m][2];
#pragma unroll
            for (int n = 0; n < 8; ++n) {
              U4[n][0] = fmaf(wm[n], g0, U4[n][0]);
              U4[n][1] = fmaf(wm[n], g1, U4[n][1]);
              U4[n][2] = fmaf(wm[n], g2, U4[n][2]);
            }
          }
        }
      }
      a0 = n0; a1_ = n1; a2 = n2; a3 = n3;
    }

    // ---- finals + epilogue ----
    if (b == 0) {
      float lg = 0.f, lv = 0.f;
#pragma unroll
      for (int n = 0; n < 8; ++n) {
        float as = fmaf(T0[n], s0, T3[n]);
        lg = fmaf(as, qd[dst * 8 + n], lg);
      }
#pragma unroll
      for (int n = 0; n < 8; ++n) {
        float cx = (U4[n][1]*s1z - U4[n][2]*s1y) * INV_SQRT2;
        float cy = (U4[n][2]*s1x - U4[n][0]*s1z) * INV_SQRT2;
        float cz = (U4[n][0]*s1y - U4[n][1]*s1x) * INV_SQRT2;
        float a0v = T1[n]*s1x + U2[n][0]*s0 + cx;
        float a1v = T1[n]*s1y + U2[n][1]*s0 + cy;
        float a2v = T1[n]*s1z + U2[n][2]*s0 + cz;
        lv = fmaf(a0v, qvd[dst*24 + n*3 + 0], lv);
        lv = fmaf(a1v, qvd[dst*24 + n*3 + 1], lv);
        lv = fmaf(a2v, qvd[dst*24 + n*3 + 2], lv);
      }
      float logit = (lg * (1.f / 32.f) +
                     lv * (0.125f * INV_SQRT24) * INV_SQRT3) * 0.25f;
      ex = __expf(logit);
      if (valid) exo[pos] = ex;
    } else {
      if (valid) {
        float a = sqrtf(ex);
        const float ss = a * (1.f / 32.f);
        const float sv = a * (0.125f * INV_SQRT24);
        float accs[8], accv[8][3];
#pragma unroll
        for (int n = 0; n < 8; ++n) {
          accs[n] = fmaf(T0[n], s0, T3[n]) * ss;
          float cx = (U4[n][1]*s1z - U4[n][2]*s1y) * INV_SQRT2;
          float cy = (U4[n][2]*s1x - U4[n][0]*s1z) * INV_SQRT2;
          float cz = (U4[n][0]*s1y - U4[n][1]*s1x) * INV_SQRT2;
          accv[n][0] = (T1[n]*s1x + U2[n][0]*s0 + cx) * sv;
          accv[n][1] = (T1[n]*s1y + U2[n][1]*s0 + cy) * sv;
          accv[n][2] = (T1[n]*s1z + U2[n][2]*s0 + cz) * sv;
        }
        float4* v4 = (float4*)(wout + (size_t)pos * 32);
        float4 o;
        o.x = accs[0]; o.y = accs[1]; o.z = accs[2]; o.w = accs[3];
        v4[0] = o;
        o.x = accs[4]; o.y = accs[5]; o.z = accs[6]; o.w = accs[7];
        v4[1] = o;
        o.x = accv[0][0]; o.y = accv[0][1]; o.z = accv[0][2]; o.w = accv[1][0];
        v4[2] = o;
        o.x = accv[1][1]; o.y = accv[1][2]; o.z = accv[2][0]; o.w = accv[2][1];
        v4[3] = o;
        o.x = accv[2][2]; o.y = accv[3][0]; o.z = accv[3][1]; o.w = accv[3][2];
        v4[4] = o;
        o.x = accv[4][0]; o.y = accv[4][1]; o.z = accv[4][2]; o.w = accv[5][0];
        v4[5] = o;
        o.x = accv[5][1]; o.y = accv[5][2]; o.z = accv[6][0]; o.w = accv[6][1];
        v4[6] = o;
        o.x = accv[6][2]; o.y = accv[7][0]; o.z = accv[7][1]; o.w = accv[7][2];
        v4[7] = o;
      }
    }
  }
}

// ---------------- gather: one wave per node, float4 x 8 rows/iter ----------------
__global__ __launch_bounds__(256) void gather_kernel(
    const int* __restrict__ off,
    const float* __restrict__ exo,
    const float* __restrict__ wout,
    float* __restrict__ out)
{
  const int tid  = threadIdx.x;
  const int wave = tid >> 6;
  const int lane = tid & 63;
  const int n = blockIdx.x * 4 + wave;
  if (n >= NN) return;
  const int start = off[n];
  const int end   = off[n + 1];
  const int cnt   = end - start;

  float zp = 0.f;
  for (int j = start + lane; j < end; j += 64) zp += exo[j];
#pragma unroll
  for (int s = 32; s >= 1; s >>= 1) zp += __shfl_xor(zp, s, 64);

  const int q  = lane & 7;   // float4 column
  const int rr = lane >> 3;  // row within group of 8
  float4 acc = {0.f, 0.f, 0.f, 0.f};
  const float4* w4 = (const float4*)wout;
  for (int j = start + rr; j < end; j += 8) {
    float4 v = w4[(size_t)j * 8 + q];
    acc.x += v.x; acc.y += v.y; acc.z += v.z; acc.w += v.w;
  }
#pragma unroll
  for (int s = 8; s < 64; s <<= 1) {
    acc.x += __shfl_xor(acc.x, s, 64);
    acc.y += __shfl_xor(acc.y, s, 64);
    acc.z += __shfl_xor(acc.z, s, 64);
    acc.w += __shfl_xor(acc.w, s, 64);
  }
  if (rr == 0) {
    float s = (cnt > 0 && zp > 0.f) ? sqrtf((float)cnt / zp) : 0.f;
    float4 o = {acc.x * s, acc.y * s, acc.z * s, acc.w * s};
    ((float4*)out)[(size_t)n * 8 + q] = o;
  }
}

extern "C" void kernel_launch(void* const* d_in, const int* in_sizes, int n_in,
                              void* d_out, int out_size, void* d_ws, size_t ws_size,
                              hipStream_t stream)
{
  const float* node_attr  = (const float*)d_in[0];
  const int*   edge_index = (const int*)  d_in[1];
  const float* edge_attr  = (const float*)d_in[2];
  const float* edge_sh    = (const float*)d_in[3];
  const float* Wq0 = (const float*)d_in[4];
  const float* Wq1 = (const float*)d_in[5];
  const float* kW1 = (const float*)d_in[6];
  const float* kW2 = (const float*)d_in[7];
  const float* vW1 = (const float*)d_in[8];
  const float* vW2 = (const float*)d_in[9];
  const float* Wd0 = (const float*)d_in[10];
  const float* Wd1 = (const float*)d_in[11];
  float* out = (float*)d_out;

  float* ws = (float*)d_ws;
  float* qd     = ws;                    // 200000
  float* qvd    = qd   + 200000;         // 600000
  unsigned short* afrag  = (unsigned short*)(qvd + 600000);   // 40960 ushorts
  unsigned short* afrag1 = afrag + 40960;                     // 4096 ushorts
  int* hist   = (int*)(afrag1 + 4096);                        // 25024
  int* off    = hist + 25024;                                 // 25056 (NN+1)
  int* cursor = off  + 25056;                                 // 25024
  float* exo  = (float*)(cursor + 25024);                     // 200000
  float* wout = exo + 200000;                                 // 6400000

  hipMemsetAsync(hist, 0, 25024 * sizeof(int), stream);

  prep_kernel<<<160, 256, 0, stream>>>(
      kW1, kW2, vW1, vW2, node_attr, Wq0, Wq1, Wd0, Wd1, edge_index,
      afrag, afrag1, qd, qvd, hist);
  scan_kernel<<<1, 1024, 0, stream>>>(hist, off, cursor);
  edge_kernel<<<(NE + 255) / 256, 256, 0, stream>>>(
      node_attr, edge_index, edge_attr, edge_sh,
      afrag1, afrag, qd, qvd, cursor, exo, wout);
  gather_kernel<<<(NN + 3) / 4, 256, 0, stream>>>(off, exo, wout, out);
}

// Round 10
// 238.713 us; speedup vs baseline: 1.7104x; 1.7104x over previous
//
#include <hip/hip_runtime.h>
#include <hip/hip_bf16.h>
#include <math.h>

#define NE 200000
#define NN 25000

static constexpr float INV_SQRT3  = 0.5773502691896258f;
static constexpr float INV_SQRT2  = 0.7071067811865476f;
static constexpr float INV_SQRT8  = 0.3535533905932738f;
static constexpr float INV_SQRT24 = 0.2041241452319315f;

typedef __attribute__((ext_vector_type(8))) short bf16x8;
typedef __attribute__((ext_vector_type(4))) float f32x4;

union U16x8 { uint4 u; bf16x8 v; };

__device__ __forceinline__ unsigned f2bf1(float f) {
  unsigned u = __float_as_uint(f);
  return (u + 0x7FFFu + ((u >> 16) & 1u)) >> 16;
}
// native v_cvt_pk_bf16_f32 (RNE): a -> low 16, b -> high 16
__device__ __forceinline__ unsigned packbf(float a, float b) {
  union { __hip_bfloat162 h; unsigned u; } c;
  c.h = __float22bfloat162_rn(make_float2(a, b));
  return c.u;
}
__device__ __forceinline__ float bflo(unsigned u) { return __uint_as_float(u << 16); }
__device__ __forceinline__ float bfhi(unsigned u) { return __uint_as_float(u & 0xFFFF0000u); }

// ---------------- fused prep: W2 A-frags + W1 A-frags + node q's + dst histogram ----
__global__ __launch_bounds__(256) void prep_kernel(
    const float* __restrict__ kW1, const float* __restrict__ kW2,
    const float* __restrict__ vW1, const float* __restrict__ vW2,
    const float* __restrict__ node_attr,
    const float* __restrict__ Wq0, const float* __restrict__ Wq1,
    const float* __restrict__ Wd0, const float* __restrict__ Wd1,
    const int*   __restrict__ edge_index,
    unsigned short* __restrict__ afrag,
    unsigned short* __restrict__ afrag1,
    float* __restrict__ qd, float* __restrict__ qvd,
    int* __restrict__ hist)
{
  int t = blockIdx.x * blockDim.x + threadIdx.x;   // 40960 threads
  if (t < 4096) {
    int j    = t & 7;
    int lane = (t >> 3) & 63;
    int rt   = (t >> 9) & 3;
    int b    = (t >> 11) & 1;
    int quad = lane >> 4;
    int k    = quad * 8 + j;
    int jeff = k & 15;
    int r    = rt * 16 + (lane & 15);
    const float* W = b ? vW1 : kW1;
    afrag1[t] = (unsigned short)f2bf1(W[jeff * 64 + r]);
  }
  if (t < 40960) {
    int j    = t & 7;
    int lane = (t >> 3) & 63;
    int kk   = (t >> 9) & 1;
    int ot   = (t >> 10) & 1;
    int ci   = t >> 11;
    int b    = ci / 10;
    int rem  = ci - b * 10;
    int p    = rem >> 1;
    int hf   = rem & 1;
    int r    = kk * 32 + ((lane >> 4) << 3) + j;
    int o    = p * 64 + hf * 32 + ot * 16 + (lane & 15);
    const float* W = b ? vW2 : kW2;
    afrag[t] = (unsigned short)f2bf1(W[r * 320 + o]);
  }
#pragma unroll
  for (int i = 0; i < 5; ++i) {
    int e = t * 5 + i;
    if (e < NE) atomicAdd(&hist[edge_index[NE + e]], 1);
  }
  if (t < NN) {
    int n = t;
    float ns[8], nv[24];
#pragma unroll
    for (int i = 0; i < 8; ++i)  ns[i] = node_attr[n * 32 + i];
#pragma unroll
    for (int i = 0; i < 24; ++i) nv[i] = node_attr[n * 32 + 8 + i];
    float qs[8];
#pragma unroll
    for (int m = 0; m < 8; ++m) {
      float a = 0.f;
#pragma unroll
      for (int i = 0; i < 8; ++i) a = fmaf(ns[i], Wq0[i * 8 + m], a);
      qs[m] = a * INV_SQRT8;
    }
#pragma unroll
    for (int k = 0; k < 8; ++k) {
      float a = 0.f;
#pragma unroll
      for (int m = 0; m < 8; ++m) a = fmaf(qs[m], Wd0[m * 8 + k], a);
      qd[n * 8 + k] = a;
    }
    float qv[24];
#pragma unroll
    for (int k = 0; k < 8; ++k) {
#pragma unroll
      for (int c = 0; c < 3; ++c) {
        float a = 0.f;
#pragma unroll
        for (int m = 0; m < 8; ++m) a = fmaf(nv[m * 3 + c], Wq1[m * 8 + k], a);
        qv[k * 3 + c] = a * INV_SQRT8;
      }
    }
#pragma unroll
    for (int k = 0; k < 8; ++k) {
#pragma unroll
      for (int c = 0; c < 3; ++c) {
        float a = 0.f;
#pragma unroll
        for (int m = 0; m < 8; ++m) a = fmaf(qv[m * 3 + c], Wd1[m * 8 + k], a);
        qvd[n * 24 + k * 3 + c] = a;
      }
    }
  }
}

// ---------------- chunked shfl scan ----------------
__global__ __launch_bounds__(1024) void scan_kernel(
    const int* __restrict__ hist, int* __restrict__ off, int* __restrict__ cursor)
{
  __shared__ int wsum[16];
  const int tid  = threadIdx.x;
  const int lane = tid & 63;
  const int wv   = tid >> 6;
  const int base = tid * 25;
  int loc[25];
  int s = 0;
#pragma unroll
  for (int i = 0; i < 25; ++i) {
    int idx = base + i;
    int v = (idx < NN) ? hist[idx] : 0;
    loc[i] = s;
    s += v;
  }
  int incl = s;
#pragma unroll
  for (int d = 1; d < 64; d <<= 1) {
    int t = __shfl_up(incl, d, 64);
    if (lane >= d) incl += t;
  }
  int wexcl = incl - s;
  if (lane == 63) wsum[wv] = incl;
  __syncthreads();
  if (wv == 0 && lane < 16) {
    int v = wsum[lane];
    int inc2 = v;
#pragma unroll
    for (int d = 1; d < 16; d <<= 1) {
      int t = __shfl_up(inc2, d, 64);
      if (lane >= d) inc2 += t;
    }
    wsum[lane] = inc2 - v;
  }
  __syncthreads();
  int tbase = wsum[wv] + wexcl;
#pragma unroll
  for (int i = 0; i < 25; ++i) {
    int idx = base + i;
    if (idx < NN) { int e = tbase + loc[i]; off[idx] = e; cursor[idx] = e; }
  }
  if (tid == 1023) off[NN] = tbase + s;
}

// ---------------- main edge pass (all-MFMA, CSR output) ----------------
// R10 = R8 structure (116 VGPR, 116 µs) + register-neutral wins only:
//  - native v_cvt_pk_bf16_f32 pack
//  - 64-thread blocks (kernel has NO barriers; 1 wave + 9216B LDS ->
//    finer scheduling, smoother ramp; 4 waves/SIMD capacity preserved)
// R9's separable accumulators (+40 VGPR) and A-frag prefetch (+16 VGPR)
// REGRESSED (208 VGPR -> 2 waves/SIMD -> 290 µs). Do not widen acc state.
__global__ __launch_bounds__(64) void edge_kernel(
    const float* __restrict__ node_attr,
    const int*   __restrict__ edge_index,
    const float* __restrict__ edge_attr,
    const float* __restrict__ edge_sh,
    const unsigned short* __restrict__ afrag1,
    const unsigned short* __restrict__ afrag,
    const float* __restrict__ qd,   const float* __restrict__ qvd,
    int* __restrict__ cursor,
    float* __restrict__ exo, float* __restrict__ wout)
{
  __shared__ unsigned char smem[9216];   // per-wave region (1 wave/block)
  const int lane = threadIdx.x;
  const int l15  = lane & 15;
  const int quad = lane >> 4;
  unsigned char* sea = smem;             // 64 x 80 B (ea hi/lo frags)
  unsigned char* sh  = smem;             // 64 x 144 B (h rows)
  unsigned char* swp = smem;             // 64 x 80 B (w chunks)

  const int e = blockIdx.x * 64 + lane;
  const bool valid = (e < NE);
  const int el  = valid ? e : (NE - 1);
  const int src = edge_index[el];
  const int dst = edge_index[NE + el];

  int pos = 0;
  if (valid) pos = atomicAdd(&cursor[dst], 1);

  const float s0  = edge_sh[el * 4 + 0];
  const float s1x = edge_sh[el * 4 + 1];
  const float s1y = edge_sh[el * 4 + 2];
  const float s1z = edge_sh[el * 4 + 3];

  // ---- stage ea as bf16 hi + lo (error-compensated) into sea ----
  {
    float ea[16];
    const float4* ea4 = (const float4*)(edge_attr + (size_t)el * 16);
#pragma unroll
    for (int i = 0; i < 4; ++i) {
      float4 v = ea4[i];
      ea[4*i+0] = v.x; ea[4*i+1] = v.y; ea[4*i+2] = v.z; ea[4*i+3] = v.w;
    }
    unsigned char* myrow = sea + lane * 80;
    unsigned hi[8];
    float lo[16];
#pragma unroll
    for (int i = 0; i < 8; ++i) {
      unsigned pk = packbf(ea[2*i], ea[2*i+1]);
      hi[i] = pk;
      lo[2*i]   = ea[2*i]   - bflo(pk);
      lo[2*i+1] = ea[2*i+1] - bfhi(pk);
    }
    uint4 w0 = {hi[0], hi[1], hi[2], hi[3]};
    uint4 w1 = {hi[4], hi[5], hi[6], hi[7]};
    *(uint4*)(myrow)      = w0;
    *(uint4*)(myrow + 16) = w1;
    uint4 w2, w3;
    w2.x = packbf(lo[0], lo[1]);   w2.y = packbf(lo[2], lo[3]);
    w2.z = packbf(lo[4], lo[5]);   w2.w = packbf(lo[6], lo[7]);
    w3.x = packbf(lo[8], lo[9]);   w3.y = packbf(lo[10], lo[11]);
    w3.z = packbf(lo[12], lo[13]); w3.w = packbf(lo[14], lo[15]);
    *(uint4*)(myrow + 32) = w2;
    *(uint4*)(myrow + 48) = w3;
  }

  // ---- B1 fragments (ea) ----
  U16x8 B1[4];
#pragma unroll
  for (int et = 0; et < 4; ++et)
    B1[et].u = *(const uint4*)(sea + (et*16 + l15) * 80 + quad * 16);

  // ---- own-edge node values ----
  float xs[8], xv[8][3];
  {
    const float4* na4 = (const float4*)(node_attr + (size_t)src * 32);
    float tmp[32];
#pragma unroll
    for (int i = 0; i < 8; ++i) {
      float4 v = na4[i];
      tmp[4*i+0] = v.x; tmp[4*i+1] = v.y; tmp[4*i+2] = v.z; tmp[4*i+3] = v.w;
    }
#pragma unroll
    for (int m = 0; m < 8; ++m) xs[m] = tmp[m];
#pragma unroll
    for (int m = 0; m < 8; ++m) {
      xv[m][0] = tmp[8 + 3*m + 0];
      xv[m][1] = tmp[8 + 3*m + 1];
      xv[m][2] = tmp[8 + 3*m + 2];
    }
  }

  const uint4* AF  = (const uint4*)afrag;
  const uint4* AF1 = (const uint4*)afrag1;
  float ex = 0.f;

#pragma unroll 1
  for (int b = 0; b < 2; ++b) {
    // ---- layer-1: h = silu(ea @ W1 / 4) via 16 MFMA, bf16 h -> sh ----
#pragma unroll 1
    for (int rt = 0; rt < 4; ++rt) {
      U16x8 a1;
      a1.u = AF1[(b * 4 + rt) * 64 + lane];
#pragma unroll
      for (int et = 0; et < 4; ++et) {
        f32x4 c = {0.f, 0.f, 0.f, 0.f};
        c = __builtin_amdgcn_mfma_f32_16x16x32_bf16(a1.v, B1[et].v, c, 0, 0, 0);
        float hh[4];
#pragma unroll
        for (int i = 0; i < 4; ++i) {
          float x = c[i] * 0.25f;
          hh[i] = x / (1.f + __expf(-x));
        }
        uint2 pk;
        pk.x = packbf(hh[0], hh[1]);
        pk.y = packbf(hh[2], hh[3]);
        *(uint2*)(sh + (et*16 + l15) * 144 + (rt*16 + quad*4) * 2) = pk;
      }
    }

    // ---- B2 fragments (H) ----
    bf16x8 B[4][2];
#pragma unroll
    for (int et = 0; et < 4; ++et) {
#pragma unroll
      for (int kk = 0; kk < 2; ++kk) {
        U16x8 cv;
        cv.u = *(const uint4*)(sh + (et*16 + l15) * 144 + kk * 64 + quad * 16);
        B[et][kk] = cv.v;
      }
    }

    float accs[8];
    float accv[8][3];
#pragma unroll
    for (int n = 0; n < 8; ++n) {
      accs[n] = 0.f;
      accv[n][0] = 0.f; accv[n][1] = 0.f; accv[n][2] = 0.f;
    }

    // ---- 10 chunks, NOT unrolled (spill control) ----
#pragma unroll 1
    for (int cc = 0; cc < 10; ++cc) {
      const int p  = cc >> 1;
      const int hf = cc & 1;
      const int ci = b * 10 + cc;
      U16x8 a00, a01, a10, a11;
      a00.u = AF[(ci*4 + 0) * 64 + lane];
      a01.u = AF[(ci*4 + 1) * 64 + lane];
      a10.u = AF[(ci*4 + 2) * 64 + lane];
      a11.u = AF[(ci*4 + 3) * 64 + lane];

#pragma unroll
      for (int et = 0; et < 4; ++et) {
        f32x4 c0 = {0.f, 0.f, 0.f, 0.f};
        f32x4 c1 = {0.f, 0.f, 0.f, 0.f};
        c0 = __builtin_amdgcn_mfma_f32_16x16x32_bf16(a00.v, B[et][0], c0, 0, 0, 0);
        c0 = __builtin_amdgcn_mfma_f32_16x16x32_bf16(a01.v, B[et][1], c0, 0, 0, 0);
        c1 = __builtin_amdgcn_mfma_f32_16x16x32_bf16(a10.v, B[et][0], c1, 0, 0, 0);
        c1 = __builtin_amdgcn_mfma_f32_16x16x32_bf16(a11.v, B[et][1], c1, 0, 0, 0);
        unsigned char* wrow = swp + (et*16 + l15) * 80;
        uint2 p0; p0.x = packbf(c0.x, c0.y); p0.y = packbf(c0.z, c0.w);
        uint2 p1; p1.x = packbf(c1.x, c1.y); p1.y = packbf(c1.z, c1.w);
        *(uint2*)(wrow + quad * 8)      = p0;
        *(uint2*)(wrow + 32 + quad * 8) = p1;
      }

      // consume w-chunk in two 16-value halves
      const uint4* wr = (const uint4*)(swp + (size_t)lane * 80);
#pragma unroll
      for (int h2 = 0; h2 < 2; ++h2) {
        uint4 qa = wr[h2 * 2], qb = wr[h2 * 2 + 1];
        float wvv[16];
        {
          unsigned qs_[8] = {qa.x,qa.y,qa.z,qa.w, qb.x,qb.y,qb.z,qb.w};
#pragma unroll
          for (int i = 0; i < 8; ++i) {
            wvv[2*i]   = bflo(qs_[i]);
            wvv[2*i+1] = bfhi(qs_[i]);
          }
        }
#pragma unroll
        for (int mm = 0; mm < 2; ++mm) {
          const int m = hf * 4 + h2 * 2 + mm;
          const float* wm = &wvv[mm * 8];
          if (p == 0) {
            float g = xs[m] * s0;
#pragma unroll
            for (int n = 0; n < 8; ++n) accs[n] = fmaf(wm[n], g, accs[n]);
          } else if (p == 1) {
            float a = xs[m];
            float gx = a * s1x, gy = a * s1y, gz = a * s1z;
#pragma unroll
            for (int n = 0; n < 8; ++n) {
              accv[n][0] = fmaf(wm[n], gx, accv[n][0]);
              accv[n][1] = fmaf(wm[n], gy, accv[n][1]);
              accv[n][2] = fmaf(wm[n], gz, accv[n][2]);
            }
          } else if (p == 2) {
            float gx = xv[m][0] * s0, gy = xv[m][1] * s0, gz = xv[m][2] * s0;
#pragma unroll
            for (int n = 0; n < 8; ++n) {
              accv[n][0] = fmaf(wm[n], gx, accv[n][0]);
              accv[n][1] = fmaf(wm[n], gy, accv[n][1]);
              accv[n][2] = fmaf(wm[n], gz, accv[n][2]);
            }
          } else if (p == 3) {
            float dm = (xv[m][0]*s1x + xv[m][1]*s1y + xv[m][2]*s1z) * INV_SQRT3;
#pragma unroll
            for (int n = 0; n < 8; ++n) accs[n] = fmaf(wm[n], dm, accs[n]);
          } else {
            float crx = (xv[m][1]*s1z - xv[m][2]*s1y) * INV_SQRT2;
            float cry = (xv[m][2]*s1x - xv[m][0]*s1z) * INV_SQRT2;
            float crz = (xv[m][0]*s1y - xv[m][1]*s1x) * INV_SQRT2;
#pragma unroll
            for (int n = 0; n < 8; ++n) {
              accv[n][0] = fmaf(wm[n], crx, accv[n][0]);
              accv[n][1] = fmaf(wm[n], cry, accv[n][1]);
              accv[n][2] = fmaf(wm[n], crz, accv[n][2]);
            }
          }
        }
      }
    }

    if (b == 0) {
      float lg = 0.f, lv = 0.f;
#pragma unroll
      for (int n = 0; n < 8; ++n) lg = fmaf(accs[n], qd[dst * 8 + n], lg);
#pragma unroll
      for (int n = 0; n < 8; ++n) {
#pragma unroll
        for (int c = 0; c < 3; ++c)
          lv = fmaf(accv[n][c], qvd[dst * 24 + n * 3 + c], lv);
      }
      float logit = (lg * (1.f / 32.f) +
                     lv * (0.125f * INV_SQRT24) * INV_SQRT3) * 0.25f;
      ex = __expf(logit);
      if (valid) exo[pos] = ex;
    } else {
      if (valid) {
        float a = sqrtf(ex);
        const float ss = a * (1.f / 32.f);
        const float sv = a * (0.125f * INV_SQRT24);
        float4* v4 = (float4*)(wout + (size_t)pos * 32);
        float4 o;
        o.x = accs[0] * ss; o.y = accs[1] * ss;
        o.z = accs[2] * ss; o.w = accs[3] * ss;
        v4[0] = o;
        o.x = accs[4] * ss; o.y = accs[5] * ss;
        o.z = accs[6] * ss; o.w = accs[7] * ss;
        v4[1] = o;
        o.x = accv[0][0] * sv; o.y = accv[0][1] * sv;
        o.z = accv[0][2] * sv; o.w = accv[1][0] * sv;
        v4[2] = o;
        o.x = accv[1][1] * sv; o.y = accv[1][2] * sv;
        o.z = accv[2][0] * sv; o.w = accv[2][1] * sv;
        v4[3] = o;
        o.x = accv[2][2] * sv; o.y = accv[3][0] * sv;
        o.z = accv[3][1] * sv; o.w = accv[3][2] * sv;
        v4[4] = o;
        o.x = accv[4][0] * sv; o.y = accv[4][1] * sv;
        o.z = accv[4][2] * sv; o.w = accv[5][0] * sv;
        v4[5] = o;
        o.x = accv[5][1] * sv; o.y = accv[5][2] * sv;
        o.z = accv[6][0] * sv; o.w = accv[6][1] * sv;
        v4[6] = o;
        o.x = accv[6][2] * sv; o.y = accv[7][0] * sv;
        o.z = accv[7][1] * sv; o.w = accv[7][2] * sv;
        v4[7] = o;
      }
    }
  }
}

// ---------------- gather: one wave per node, float4 x 8 rows/iter ----------------
__global__ __launch_bounds__(256) void gather_kernel(
    const int* __restrict__ off,
    const float* __restrict__ exo,
    const float* __restrict__ wout,
    float* __restrict__ out)
{
  const int tid  = threadIdx.x;
  const int wave = tid >> 6;
  const int lane = tid & 63;
  const int n = blockIdx.x * 4 + wave;
  if (n >= NN) return;
  const int start = off[n];
  const int end   = off[n + 1];
  const int cnt   = end - start;

  float zp = 0.f;
  for (int j = start + lane; j < end; j += 64) zp += exo[j];
#pragma unroll
  for (int s = 32; s >= 1; s >>= 1) zp += __shfl_xor(zp, s, 64);

  const int q  = lane & 7;   // float4 column
  const int rr = lane >> 3;  // row within group of 8
  float4 acc = {0.f, 0.f, 0.f, 0.f};
  const float4* w4 = (const float4*)wout;
  for (int j = start + rr; j < end; j += 8) {
    float4 v = w4[(size_t)j * 8 + q];
    acc.x += v.x; acc.y += v.y; acc.z += v.z; acc.w += v.w;
  }
#pragma unroll
  for (int s = 8; s < 64; s <<= 1) {
    acc.x += __shfl_xor(acc.x, s, 64);
    acc.y += __shfl_xor(acc.y, s, 64);
    acc.z += __shfl_xor(acc.z, s, 64);
    acc.w += __shfl_xor(acc.w, s, 64);
  }
  if (rr == 0) {
    float s = (cnt > 0 && zp > 0.f) ? sqrtf((float)cnt / zp) : 0.f;
    float4 o = {acc.x * s, acc.y * s, acc.z * s, acc.w * s};
    ((float4*)out)[(size_t)n * 8 + q] = o;
  }
}

extern "C" void kernel_launch(void* const* d_in, const int* in_sizes, int n_in,
                              void* d_out, int out_size, void* d_ws, size_t ws_size,
                              hipStream_t stream)
{
  const float* node_attr  = (const float*)d_in[0];
  const int*   edge_index = (const int*)  d_in[1];
  const float* edge_attr  = (const float*)d_in[2];
  const float* edge_sh    = (const float*)d_in[3];
  const float* Wq0 = (const float*)d_in[4];
  const float* Wq1 = (const float*)d_in[5];
  const float* kW1 = (const float*)d_in[6];
  const float* kW2 = (const float*)d_in[7];
  const float* vW1 = (const float*)d_in[8];
  const float* vW2 = (const float*)d_in[9];
  const float* Wd0 = (const float*)d_in[10];
  const float* Wd1 = (const float*)d_in[11];
  float* out = (float*)d_out;

  float* ws = (float*)d_ws;
  float* qd     = ws;                    // 200000
  float* qvd    = qd   + 200000;         // 600000
  unsigned short* afrag  = (unsigned short*)(qvd + 600000);   // 40960 ushorts
  unsigned short* afrag1 = afrag + 40960;                     // 4096 ushorts
  int* hist   = (int*)(afrag1 + 4096);                        // 25024
  int* off    = hist + 25024;                                 // 25056 (NN+1)
  int* cursor = off  + 25056;                                 // 25024
  float* exo  = (float*)(cursor + 25024);                     // 200000
  float* wout = exo + 200000;                                 // 6400000

  hipMemsetAsync(hist, 0, 25024 * sizeof(int), stream);

  prep_kernel<<<160, 256, 0, stream>>>(
      kW1, kW2, vW1, vW2, node_attr, Wq0, Wq1, Wd0, Wd1, edge_index,
      afrag, afrag1, qd, qvd, hist);
  scan_kernel<<<1, 1024, 0, stream>>>(hist, off, cursor);
  edge_kernel<<<(NE + 63) / 64, 64, 0, stream>>>(
      node_attr, edge_index, edge_attr, edge_sh,
      afrag1, afrag, qd, qvd, cursor, exo, wout);
  gather_kernel<<<(NN + 3) / 4, 256, 0, stream>>>(off, exo, wout, out);
}

// Round 11
// 220.723 us; speedup vs baseline: 1.8498x; 1.0815x over previous
//
#include <hip/hip_runtime.h>
#include <hip/hip_bf16.h>
#include <math.h>

#define NE 200000
#define NN 25000

static constexpr float INV_SQRT3  = 0.5773502691896258f;
static constexpr float INV_SQRT2  = 0.7071067811865476f;
static constexpr float INV_SQRT8  = 0.3535533905932738f;
static constexpr float INV_SQRT24 = 0.2041241452319315f;

typedef __attribute__((ext_vector_type(8))) short bf16x8;
typedef __attribute__((ext_vector_type(4))) float f32x4;

union U16x8 { uint4 u; bf16x8 v; };

__device__ __forceinline__ unsigned f2bf1(float f) {
  unsigned u = __float_as_uint(f);
  return (u + 0x7FFFu + ((u >> 16) & 1u)) >> 16;
}
// native v_cvt_pk_bf16_f32 (RNE): a -> low 16, b -> high 16
__device__ __forceinline__ unsigned packbf(float a, float b) {
  union { __hip_bfloat162 h; unsigned u; } c;
  c.h = __float22bfloat162_rn(make_float2(a, b));
  return c.u;
}
__device__ __forceinline__ float bflo(unsigned u) { return __uint_as_float(u << 16); }
__device__ __forceinline__ float bfhi(unsigned u) { return __uint_as_float(u & 0xFFFF0000u); }

// ---------------- fused prep: W2 A-frags + W1 A-frags + dst histogram + node q's ----
// R11: thread ranges split — t<40960 does frags+hist, t-40960<NN does node-q
// (R10's 160-block grid left 96 CUs idle and serialized q behind hist).
__global__ __launch_bounds__(256) void prep_kernel(
    const float* __restrict__ kW1, const float* __restrict__ kW2,
    const float* __restrict__ vW1, const float* __restrict__ vW2,
    const float* __restrict__ node_attr,
    const float* __restrict__ Wq0, const float* __restrict__ Wq1,
    const float* __restrict__ Wd0, const float* __restrict__ Wd1,
    const int*   __restrict__ edge_index,
    unsigned short* __restrict__ afrag,
    unsigned short* __restrict__ afrag1,
    float* __restrict__ qd, float* __restrict__ qvd,
    int* __restrict__ hist)
{
  int t = blockIdx.x * blockDim.x + threadIdx.x;   // 66304 threads
  if (t < 4096) {
    int j    = t & 7;
    int lane = (t >> 3) & 63;
    int rt   = (t >> 9) & 3;
    int b    = (t >> 11) & 1;
    int quad = lane >> 4;
    int k    = quad * 8 + j;
    int jeff = k & 15;
    int r    = rt * 16 + (lane & 15);
    const float* W = b ? vW1 : kW1;
    afrag1[t] = (unsigned short)f2bf1(W[jeff * 64 + r]);
  }
  if (t < 40960) {
    int j    = t & 7;
    int lane = (t >> 3) & 63;
    int kk   = (t >> 9) & 1;
    int ot   = (t >> 10) & 1;
    int ci   = t >> 11;
    int b    = ci / 10;
    int rem  = ci - b * 10;
    int p    = rem >> 1;
    int hf   = rem & 1;
    int r    = kk * 32 + ((lane >> 4) << 3) + j;
    int o    = p * 64 + hf * 32 + ot * 16 + (lane & 15);
    const float* W = b ? vW2 : kW2;
    afrag[t] = (unsigned short)f2bf1(W[r * 320 + o]);
#pragma unroll
    for (int i = 0; i < 5; ++i) {
      int e = t * 5 + i;
      if (e < NE) atomicAdd(&hist[edge_index[NE + e]], 1);
    }
  }
  int tn = t - 40960;
  if (tn >= 0 && tn < NN) {
    int n = tn;
    float ns[8], nv[24];
#pragma unroll
    for (int i = 0; i < 8; ++i)  ns[i] = node_attr[n * 32 + i];
#pragma unroll
    for (int i = 0; i < 24; ++i) nv[i] = node_attr[n * 32 + 8 + i];
    float qs[8];
#pragma unroll
    for (int m = 0; m < 8; ++m) {
      float a = 0.f;
#pragma unroll
      for (int i = 0; i < 8; ++i) a = fmaf(ns[i], Wq0[i * 8 + m], a);
      qs[m] = a * INV_SQRT8;
    }
#pragma unroll
    for (int k = 0; k < 8; ++k) {
      float a = 0.f;
#pragma unroll
      for (int m = 0; m < 8; ++m) a = fmaf(qs[m], Wd0[m * 8 + k], a);
      qd[n * 8 + k] = a;
    }
    float qv[24];
#pragma unroll
    for (int k = 0; k < 8; ++k) {
#pragma unroll
      for (int c = 0; c < 3; ++c) {
        float a = 0.f;
#pragma unroll
        for (int m = 0; m < 8; ++m) a = fmaf(nv[m * 3 + c], Wq1[m * 8 + k], a);
        qv[k * 3 + c] = a * INV_SQRT8;
      }
    }
#pragma unroll
    for (int k = 0; k < 8; ++k) {
#pragma unroll
      for (int c = 0; c < 3; ++c) {
        float a = 0.f;
#pragma unroll
        for (int m = 0; m < 8; ++m) a = fmaf(qv[m * 3 + c], Wd1[m * 8 + k], a);
        qvd[n * 24 + k * 3 + c] = a;
      }
    }
  }
}

// ---------------- chunked shfl scan: 32 elems/thread via aligned int4 ----------------
// hist is allocated/zeroed to 25024 so the int4 tail reads land on zeros.
__global__ __launch_bounds__(1024) void scan_kernel(
    const int* __restrict__ hist, int* __restrict__ off, int* __restrict__ cursor)
{
  __shared__ int wsum[16];
  const int tid  = threadIdx.x;
  const int lane = tid & 63;
  const int wv   = tid >> 6;
  const int base = tid * 32;
  int loc[32];
  int s = 0;
  if (base < NN) {
    const int4* h4 = (const int4*)(hist + base);
#pragma unroll
    for (int q = 0; q < 8; ++q) {
      int4 v4 = h4[q];
      loc[4*q+0] = s; s += v4.x;
      loc[4*q+1] = s; s += v4.y;
      loc[4*q+2] = s; s += v4.z;
      loc[4*q+3] = s; s += v4.w;
    }
  } else {
#pragma unroll
    for (int i = 0; i < 32; ++i) loc[i] = 0;
  }
  int incl = s;
#pragma unroll
  for (int d = 1; d < 64; d <<= 1) {
    int t = __shfl_up(incl, d, 64);
    if (lane >= d) incl += t;
  }
  int wexcl = incl - s;
  if (lane == 63) wsum[wv] = incl;
  __syncthreads();
  if (wv == 0 && lane < 16) {
    int v = wsum[lane];
    int inc2 = v;
#pragma unroll
    for (int d = 1; d < 16; d <<= 1) {
      int t = __shfl_up(inc2, d, 64);
      if (lane >= d) inc2 += t;
    }
    wsum[lane] = inc2 - v;
  }
  __syncthreads();
  int tbase = wsum[wv] + wexcl;
  if (base < NN) {
#pragma unroll
    for (int i = 0; i < 32; ++i) {
      int idx = base + i;
      if (idx < NN) { int e2 = tbase + loc[i]; off[idx] = e2; cursor[idx] = e2; }
    }
  }
  if (tid == 1023) off[NN] = tbase + s;
}

// ---------------- main edge pass (all-MFMA, CSR output) ----------------
// R11: w-chunks staged through LDS in raw f32 (stride 144 B = 16-aligned,
// bank-even). Kills the per-chunk bf16 pack (8 cvt_pk) + unpack (32
// shift/and) that cost ~1000+ VALU inst/edge in R10. Everything else = R10
// (112 VGPR, 64-thread blocks, no barriers). Do NOT widen accumulator
// state (R9: +56 VGPR -> 2 waves/SIMD -> 2.7x regression).
__global__ __launch_bounds__(64) void edge_kernel(
    const float* __restrict__ node_attr,
    const int*   __restrict__ edge_index,
    const float* __restrict__ edge_attr,
    const float* __restrict__ edge_sh,
    const unsigned short* __restrict__ afrag1,
    const unsigned short* __restrict__ afrag,
    const float* __restrict__ qd,   const float* __restrict__ qvd,
    int* __restrict__ cursor,
    float* __restrict__ exo, float* __restrict__ wout)
{
  __shared__ unsigned char smem[9216];   // per-wave region (1 wave/block)
  const int lane = threadIdx.x;
  const int l15  = lane & 15;
  const int quad = lane >> 4;
  unsigned char* sea = smem;             // 64 x 80 B  (ea hi/lo frags)
  unsigned char* sh  = smem;             // 64 x 144 B (h rows, bf16)
  unsigned char* swp = smem;             // 64 x 144 B (w chunks, f32: 32 x 4B used)

  const int e = blockIdx.x * 64 + lane;
  const bool valid = (e < NE);
  const int el  = valid ? e : (NE - 1);
  const int src = edge_index[el];
  const int dst = edge_index[NE + el];

  int pos = 0;
  if (valid) pos = atomicAdd(&cursor[dst], 1);

  const float s0  = edge_sh[el * 4 + 0];
  const float s1x = edge_sh[el * 4 + 1];
  const float s1y = edge_sh[el * 4 + 2];
  const float s1z = edge_sh[el * 4 + 3];

  // ---- stage ea as bf16 hi + lo (error-compensated) into sea ----
  {
    float ea[16];
    const float4* ea4 = (const float4*)(edge_attr + (size_t)el * 16);
#pragma unroll
    for (int i = 0; i < 4; ++i) {
      float4 v = ea4[i];
      ea[4*i+0] = v.x; ea[4*i+1] = v.y; ea[4*i+2] = v.z; ea[4*i+3] = v.w;
    }
    unsigned char* myrow = sea + lane * 80;
    unsigned hi[8];
    float lo[16];
#pragma unroll
    for (int i = 0; i < 8; ++i) {
      unsigned pk = packbf(ea[2*i], ea[2*i+1]);
      hi[i] = pk;
      lo[2*i]   = ea[2*i]   - bflo(pk);
      lo[2*i+1] = ea[2*i+1] - bfhi(pk);
    }
    uint4 w0 = {hi[0], hi[1], hi[2], hi[3]};
    uint4 w1 = {hi[4], hi[5], hi[6], hi[7]};
    *(uint4*)(myrow)      = w0;
    *(uint4*)(myrow + 16) = w1;
    uint4 w2, w3;
    w2.x = packbf(lo[0], lo[1]);   w2.y = packbf(lo[2], lo[3]);
    w2.z = packbf(lo[4], lo[5]);   w2.w = packbf(lo[6], lo[7]);
    w3.x = packbf(lo[8], lo[9]);   w3.y = packbf(lo[10], lo[11]);
    w3.z = packbf(lo[12], lo[13]); w3.w = packbf(lo[14], lo[15]);
    *(uint4*)(myrow + 32) = w2;
    *(uint4*)(myrow + 48) = w3;
  }

  // ---- B1 fragments (ea) ----
  U16x8 B1[4];
#pragma unroll
  for (int et = 0; et < 4; ++et)
    B1[et].u = *(const uint4*)(sea + (et*16 + l15) * 80 + quad * 16);

  // ---- own-edge node values ----
  float xs[8], xv[8][3];
  {
    const float4* na4 = (const float4*)(node_attr + (size_t)src * 32);
    float tmp[32];
#pragma unroll
    for (int i = 0; i < 8; ++i) {
      float4 v = na4[i];
      tmp[4*i+0] = v.x; tmp[4*i+1] = v.y; tmp[4*i+2] = v.z; tmp[4*i+3] = v.w;
    }
#pragma unroll
    for (int m = 0; m < 8; ++m) xs[m] = tmp[m];
#pragma unroll
    for (int m = 0; m < 8; ++m) {
      xv[m][0] = tmp[8 + 3*m + 0];
      xv[m][1] = tmp[8 + 3*m + 1];
      xv[m][2] = tmp[8 + 3*m + 2];
    }
  }

  const uint4* AF  = (const uint4*)afrag;
  const uint4* AF1 = (const uint4*)afrag1;
  float ex = 0.f;

#pragma unroll 1
  for (int b = 0; b < 2; ++b) {
    // ---- layer-1: h = silu(ea @ W1 / 4) via 16 MFMA, bf16 h -> sh ----
#pragma unroll 1
    for (int rt = 0; rt < 4; ++rt) {
      U16x8 a1;
      a1.u = AF1[(b * 4 + rt) * 64 + lane];
#pragma unroll
      for (int et = 0; et < 4; ++et) {
        f32x4 c = {0.f, 0.f, 0.f, 0.f};
        c = __builtin_amdgcn_mfma_f32_16x16x32_bf16(a1.v, B1[et].v, c, 0, 0, 0);
        float hh[4];
#pragma unroll
        for (int i = 0; i < 4; ++i) {
          float x = c[i] * 0.25f;
          hh[i] = x / (1.f + __expf(-x));
        }
        uint2 pk;
        pk.x = packbf(hh[0], hh[1]);
        pk.y = packbf(hh[2], hh[3]);
        *(uint2*)(sh + (et*16 + l15) * 144 + (rt*16 + quad*4) * 2) = pk;
      }
    }

    // ---- B2 fragments (H) ----
    bf16x8 B[4][2];
#pragma unroll
    for (int et = 0; et < 4; ++et) {
#pragma unroll
      for (int kk = 0; kk < 2; ++kk) {
        U16x8 cv;
        cv.u = *(const uint4*)(sh + (et*16 + l15) * 144 + kk * 64 + quad * 16);
        B[et][kk] = cv.v;
      }
    }

    float accs[8];
    float accv[8][3];
#pragma unroll
    for (int n = 0; n < 8; ++n) {
      accs[n] = 0.f;
      accv[n][0] = 0.f; accv[n][1] = 0.f; accv[n][2] = 0.f;
    }

    // ---- 10 chunks, NOT unrolled (spill control) ----
#pragma unroll 1
    for (int cc = 0; cc < 10; ++cc) {
      const int p  = cc >> 1;
      const int hf = cc & 1;
      const int ci = b * 10 + cc;
      U16x8 a00, a01, a10, a11;
      a00.u = AF[(ci*4 + 0) * 64 + lane];
      a01.u = AF[(ci*4 + 1) * 64 + lane];
      a10.u = AF[(ci*4 + 2) * 64 + lane];
      a11.u = AF[(ci*4 + 3) * 64 + lane];

      // C stays f32: row = edge*144, [0,64) = o 0-15, [64,128) = o 16-31
#pragma unroll
      for (int et = 0; et < 4; ++et) {
        f32x4 c0 = {0.f, 0.f, 0.f, 0.f};
        f32x4 c1 = {0.f, 0.f, 0.f, 0.f};
        c0 = __builtin_amdgcn_mfma_f32_16x16x32_bf16(a00.v, B[et][0], c0, 0, 0, 0);
        c0 = __builtin_amdgcn_mfma_f32_16x16x32_bf16(a01.v, B[et][1], c0, 0, 0, 0);
        c1 = __builtin_amdgcn_mfma_f32_16x16x32_bf16(a10.v, B[et][0], c1, 0, 0, 0);
        c1 = __builtin_amdgcn_mfma_f32_16x16x32_bf16(a11.v, B[et][1], c1, 0, 0, 0);
        unsigned char* wrow = swp + (et*16 + l15) * 144;
        *(f32x4*)(wrow + quad * 16)      = c0;   // o = quad*4 + 0..3
        *(f32x4*)(wrow + 64 + quad * 16) = c1;   // o = 16 + quad*4 + 0..3
      }

      // consume w-chunk: direct f32 reads, no unpack
      const float4* wr = (const float4*)(swp + (size_t)lane * 144);
#pragma unroll
      for (int h2 = 0; h2 < 2; ++h2) {
        float4 qa = wr[h2*4+0], qb = wr[h2*4+1];
        float4 qc = wr[h2*4+2], qd2 = wr[h2*4+3];
        float wvv[16] = {qa.x,qa.y,qa.z,qa.w, qb.x,qb.y,qb.z,qb.w,
                         qc.x,qc.y,qc.z,qc.w, qd2.x,qd2.y,qd2.z,qd2.w};
#pragma unroll
        for (int mm = 0; mm < 2; ++mm) {
          const int m = hf * 4 + h2 * 2 + mm;
          const float* wm = &wvv[mm * 8];
          if (p == 0) {
            float g = xs[m] * s0;
#pragma unroll
            for (int n = 0; n < 8; ++n) accs[n] = fmaf(wm[n], g, accs[n]);
          } else if (p == 1) {
            float a = xs[m];
            float gx = a * s1x, gy = a * s1y, gz = a * s1z;
#pragma unroll
            for (int n = 0; n < 8; ++n) {
              accv[n][0] = fmaf(wm[n], gx, accv[n][0]);
              accv[n][1] = fmaf(wm[n], gy, accv[n][1]);
              accv[n][2] = fmaf(wm[n], gz, accv[n][2]);
            }
          } else if (p == 2) {
            float gx = xv[m][0] * s0, gy = xv[m][1] * s0, gz = xv[m][2] * s0;
#pragma unroll
            for (int n = 0; n < 8; ++n) {
              accv[n][0] = fmaf(wm[n], gx, accv[n][0]);
              accv[n][1] = fmaf(wm[n], gy, accv[n][1]);
              accv[n][2] = fmaf(wm[n], gz, accv[n][2]);
            }
          } else if (p == 3) {
            float dm = (xv[m][0]*s1x + xv[m][1]*s1y + xv[m][2]*s1z) * INV_SQRT3;
#pragma unroll
            for (int n = 0; n < 8; ++n) accs[n] = fmaf(wm[n], dm, accs[n]);
          } else {
            float crx = (xv[m][1]*s1z - xv[m][2]*s1y) * INV_SQRT2;
            float cry = (xv[m][2]*s1x - xv[m][0]*s1z) * INV_SQRT2;
            float crz = (xv[m][0]*s1y - xv[m][1]*s1x) * INV_SQRT2;
#pragma unroll
            for (int n = 0; n < 8; ++n) {
              accv[n][0] = fmaf(wm[n], crx, accv[n][0]);
              accv[n][1] = fmaf(wm[n], cry, accv[n][1]);
              accv[n][2] = fmaf(wm[n], crz, accv[n][2]);
            }
          }
        }
      }
    }

    if (b == 0) {
      float lg = 0.f, lv = 0.f;
#pragma unroll
      for (int n = 0; n < 8; ++n) lg = fmaf(accs[n], qd[dst * 8 + n], lg);
#pragma unroll
      for (int n = 0; n < 8; ++n) {
#pragma unroll
        for (int c = 0; c < 3; ++c)
          lv = fmaf(accv[n][c], qvd[dst * 24 + n * 3 + c], lv);
      }
      float logit = (lg * (1.f / 32.f) +
                     lv * (0.125f * INV_SQRT24) * INV_SQRT3) * 0.25f;
      ex = __expf(logit);
      if (valid) exo[pos] = ex;
    } else {
      if (valid) {
        float a = sqrtf(ex);
        const float ss = a * (1.f / 32.f);
        const float sv = a * (0.125f * INV_SQRT24);
        float4* v4 = (float4*)(wout + (size_t)pos * 32);
        float4 o;
        o.x = accs[0] * ss; o.y = accs[1] * ss;
        o.z = accs[2] * ss; o.w = accs[3] * ss;
        v4[0] = o;
        o.x = accs[4] * ss; o.y = accs[5] * ss;
        o.z = accs[6] * ss; o.w = accs[7] * ss;
        v4[1] = o;
        o.x = accv[0][0] * sv; o.y = accv[0][1] * sv;
        o.z = accv[0][2] * sv; o.w = accv[1][0] * sv;
        v4[2] = o;
        o.x = accv[1][1] * sv; o.y = accv[1][2] * sv;
        o.z = accv[2][0] * sv; o.w = accv[2][1] * sv;
        v4[3] = o;
        o.x = accv[2][2] * sv; o.y = accv[3][0] * sv;
        o.z = accv[3][1] * sv; o.w = accv[3][2] * sv;
        v4[4] = o;
        o.x = accv[4][0] * sv; o.y = accv[4][1] * sv;
        o.z = accv[4][2] * sv; o.w = accv[5][0] * sv;
        v4[5] = o;
        o.x = accv[5][1] * sv; o.y = accv[5][2] * sv;
        o.z = accv[6][0] * sv; o.w = accv[6][1] * sv;
        v4[6] = o;
        o.x = accv[6][2] * sv; o.y = accv[7][0] * sv;
        o.z = accv[7][1] * sv; o.w = accv[7][2] * sv;
        v4[7] = o;
      }
    }
  }
}

// ---------------- gather: one wave per node, float4 x 8 rows/iter ----------------
__global__ __launch_bounds__(256) void gather_kernel(
    const int* __restrict__ off,
    const float* __restrict__ exo,
    const float* __restrict__ wout,
    float* __restrict__ out)
{
  const int tid  = threadIdx.x;
  const int wave = tid >> 6;
  const int lane = tid & 63;
  const int n = blockIdx.x * 4 + wave;
  if (n >= NN) return;
  const int start = off[n];
  const int end   = off[n + 1];
  const int cnt   = end - start;

  float zp = 0.f;
  for (int j = start + lane; j < end; j += 64) zp += exo[j];
#pragma unroll
  for (int s = 32; s >= 1; s >>= 1) zp += __shfl_xor(zp, s, 64);

  const int q  = lane & 7;   // float4 column
  const int rr = lane >> 3;  // row within group of 8
  float4 acc = {0.f, 0.f, 0.f, 0.f};
  const float4* w4 = (const float4*)wout;
  for (int j = start + rr; j < end; j += 8) {
    float4 v = w4[(size_t)j * 8 + q];
    acc.x += v.x; acc.y += v.y; acc.z += v.z; acc.w += v.w;
  }
#pragma unroll
  for (int s = 8; s < 64; s <<= 1) {
    acc.x += __shfl_xor(acc.x, s, 64);
    acc.y += __shfl_xor(acc.y, s, 64);
    acc.z += __shfl_xor(acc.z, s, 64);
    acc.w += __shfl_xor(acc.w, s, 64);
  }
  if (rr == 0) {
    float s = (cnt > 0 && zp > 0.f) ? sqrtf((float)cnt / zp) : 0.f;
    float4 o = {acc.x * s, acc.y * s, acc.z * s, acc.w * s};
    ((float4*)out)[(size_t)n * 8 + q] = o;
  }
}

extern "C" void kernel_launch(void* const* d_in, const int* in_sizes, int n_in,
                              void* d_out, int out_size, void* d_ws, size_t ws_size,
                              hipStream_t stream)
{
  const float* node_attr  = (const float*)d_in[0];
  const int*   edge_index = (const int*)  d_in[1];
  const float* edge_attr  = (const float*)d_in[2];
  const float* edge_sh    = (const float*)d_in[3];
  const float* Wq0 = (const float*)d_in[4];
  const float* Wq1 = (const float*)d_in[5];
  const float* kW1 = (const float*)d_in[6];
  const float* kW2 = (const float*)d_in[7];
  const float* vW1 = (const float*)d_in[8];
  const float* vW2 = (const float*)d_in[9];
  const float* Wd0 = (const float*)d_in[10];
  const float* Wd1 = (const float*)d_in[11];
  float* out = (float*)d_out;

  float* ws = (float*)d_ws;
  float* qd     = ws;                    // 200000
  float* qvd    = qd   + 200000;         // 600000
  unsigned short* afrag  = (unsigned short*)(qvd + 600000);   // 40960 ushorts
  unsigned short* afrag1 = afrag + 40960;                     // 4096 ushorts
  int* hist   = (int*)(afrag1 + 4096);                        // 25024 (zero-padded past NN)
  int* off    = hist + 25024;                                 // 25056 (NN+1)
  int* cursor = off  + 25056;                                 // 25024
  float* exo  = (float*)(cursor + 25024);                     // 200000
  float* wout = exo + 200000;                                 // 6400000

  hipMemsetAsync(hist, 0, 25024 * sizeof(int), stream);

  prep_kernel<<<259, 256, 0, stream>>>(
      kW1, kW2, vW1, vW2, node_attr, Wq0, Wq1, Wd0, Wd1, edge_index,
      afrag, afrag1, qd, qvd, hist);
  scan_kernel<<<1, 1024, 0, stream>>>(hist, off, cursor);
  edge_kernel<<<(NE + 63) / 64, 64, 0, stream>>>(
      node_attr, edge_index, edge_attr, edge_sh,
      afrag1, afrag, qd, qvd, cursor, exo, wout);
  gather_kernel<<<(NN + 3) / 4, 256, 0, stream>>>(off, exo, wout, out);
}

// Round 12
// 209.610 us; speedup vs baseline: 1.9479x; 1.0530x over previous
//
#include <hip/hip_runtime.h>
#include <hip/hip_bf16.h>
#include <math.h>

#define NE 200000
#define NN 25000

static constexpr float INV_SQRT3  = 0.5773502691896258f;
static constexpr float INV_SQRT2  = 0.7071067811865476f;
static constexpr float INV_SQRT8  = 0.3535533905932738f;
static constexpr float INV_SQRT24 = 0.2041241452319315f;

typedef __attribute__((ext_vector_type(8))) short bf16x8;
typedef __attribute__((ext_vector_type(4))) float f32x4;

union U16x8 { uint4 u; bf16x8 v; };

__device__ __forceinline__ unsigned f2bf1(float f) {
  unsigned u = __float_as_uint(f);
  return (u + 0x7FFFu + ((u >> 16) & 1u)) >> 16;
}
// native v_cvt_pk_bf16_f32 (RNE): a -> low 16, b -> high 16
__device__ __forceinline__ unsigned packbf(float a, float b) {
  union { __hip_bfloat162 h; unsigned u; } c;
  c.h = __float22bfloat162_rn(make_float2(a, b));
  return c.u;
}
__device__ __forceinline__ float bflo(unsigned u) { return __uint_as_float(u << 16); }
__device__ __forceinline__ float bfhi(unsigned u) { return __uint_as_float(u & 0xFFFF0000u); }

// ---------------- fused prep: W2 A-frags + W1 A-frags + dst histogram + node q's ----
__global__ __launch_bounds__(256) void prep_kernel(
    const float* __restrict__ kW1, const float* __restrict__ kW2,
    const float* __restrict__ vW1, const float* __restrict__ vW2,
    const float* __restrict__ node_attr,
    const float* __restrict__ Wq0, const float* __restrict__ Wq1,
    const float* __restrict__ Wd0, const float* __restrict__ Wd1,
    const int*   __restrict__ edge_index,
    unsigned short* __restrict__ afrag,
    unsigned short* __restrict__ afrag1,
    float* __restrict__ qd, float* __restrict__ qvd,
    int* __restrict__ hist)
{
  int t = blockIdx.x * blockDim.x + threadIdx.x;   // 66304 threads
  if (t < 4096) {
    int j    = t & 7;
    int lane = (t >> 3) & 63;
    int rt   = (t >> 9) & 3;
    int b    = (t >> 11) & 1;
    int quad = lane >> 4;
    int k    = quad * 8 + j;
    int jeff = k & 15;
    int r    = rt * 16 + (lane & 15);
    const float* W = b ? vW1 : kW1;
    afrag1[t] = (unsigned short)f2bf1(W[jeff * 64 + r]);
  }
  if (t < 40960) {
    int j    = t & 7;
    int lane = (t >> 3) & 63;
    int kk   = (t >> 9) & 1;
    int ot   = (t >> 10) & 1;
    int ci   = t >> 11;
    int b    = ci / 10;
    int rem  = ci - b * 10;
    int p    = rem >> 1;
    int hf   = rem & 1;
    int r    = kk * 32 + ((lane >> 4) << 3) + j;
    int o    = p * 64 + hf * 32 + ot * 16 + (lane & 15);
    const float* W = b ? vW2 : kW2;
    afrag[t] = (unsigned short)f2bf1(W[r * 320 + o]);
#pragma unroll
    for (int i = 0; i < 5; ++i) {
      int e = t * 5 + i;
      if (e < NE) atomicAdd(&hist[edge_index[NE + e]], 1);
    }
  }
  int tn = t - 40960;
  if (tn >= 0 && tn < NN) {
    int n = tn;
    float ns[8], nv[24];
#pragma unroll
    for (int i = 0; i < 8; ++i)  ns[i] = node_attr[n * 32 + i];
#pragma unroll
    for (int i = 0; i < 24; ++i) nv[i] = node_attr[n * 32 + 8 + i];
    float qs[8];
#pragma unroll
    for (int m = 0; m < 8; ++m) {
      float a = 0.f;
#pragma unroll
      for (int i = 0; i < 8; ++i) a = fmaf(ns[i], Wq0[i * 8 + m], a);
      qs[m] = a * INV_SQRT8;
    }
#pragma unroll
    for (int k = 0; k < 8; ++k) {
      float a = 0.f;
#pragma unroll
      for (int m = 0; m < 8; ++m) a = fmaf(qs[m], Wd0[m * 8 + k], a);
      qd[n * 8 + k] = a;
    }
    float qv[24];
#pragma unroll
    for (int k = 0; k < 8; ++k) {
#pragma unroll
      for (int c = 0; c < 3; ++c) {
        float a = 0.f;
#pragma unroll
        for (int m = 0; m < 8; ++m) a = fmaf(nv[m * 3 + c], Wq1[m * 8 + k], a);
        qv[k * 3 + c] = a * INV_SQRT8;
      }
    }
#pragma unroll
    for (int k = 0; k < 8; ++k) {
#pragma unroll
      for (int c = 0; c < 3; ++c) {
        float a = 0.f;
#pragma unroll
        for (int m = 0; m < 8; ++m) a = fmaf(qv[m * 3 + c], Wd1[m * 8 + k], a);
        qvd[n * 24 + k * 3 + c] = a;
      }
    }
  }
}

// ---------------- chunked shfl scan: 32 elems/thread via aligned int4 ----------------
__global__ __launch_bounds__(1024) void scan_kernel(
    const int* __restrict__ hist, int* __restrict__ off, int* __restrict__ cursor)
{
  __shared__ int wsum[16];
  const int tid  = threadIdx.x;
  const int lane = tid & 63;
  const int wv   = tid >> 6;
  const int base = tid * 32;
  int loc[32];
  int s = 0;
  if (base < NN) {
    const int4* h4 = (const int4*)(hist + base);
#pragma unroll
    for (int q = 0; q < 8; ++q) {
      int4 v4 = h4[q];
      loc[4*q+0] = s; s += v4.x;
      loc[4*q+1] = s; s += v4.y;
      loc[4*q+2] = s; s += v4.z;
      loc[4*q+3] = s; s += v4.w;
    }
  } else {
#pragma unroll
    for (int i = 0; i < 32; ++i) loc[i] = 0;
  }
  int incl = s;
#pragma unroll
  for (int d = 1; d < 64; d <<= 1) {
    int t = __shfl_up(incl, d, 64);
    if (lane >= d) incl += t;
  }
  int wexcl = incl - s;
  if (lane == 63) wsum[wv] = incl;
  __syncthreads();
  if (wv == 0 && lane < 16) {
    int v = wsum[lane];
    int inc2 = v;
#pragma unroll
    for (int d = 1; d < 16; d <<= 1) {
      int t = __shfl_up(inc2, d, 64);
      if (lane >= d) inc2 += t;
    }
    wsum[lane] = inc2 - v;
  }
  __syncthreads();
  int tbase = wsum[wv] + wexcl;
  if (base < NN) {
#pragma unroll
    for (int i = 0; i < 32; ++i) {
      int idx = base + i;
      if (idx < NN) { int e2 = tbase + loc[i]; off[idx] = e2; cursor[idx] = e2; }
    }
  }
  if (tid == 1023) off[NN] = tbase + s;
}

// ---------------- main edge pass (all-MFMA, CSR output) ----------------
// R12 = R11 + zero-register software prefetch:
//  - chunk-0 A-frags issued before the L1 loop (hidden behind ~2K cyc of L1)
//  - next chunk's A-frags loaded into the SAME a00..a11 registers right after
//    the first-half LDS reads (a-regs are dead post-MFMA) -> L2 latency
//    overlaps the contraction VALU at no VGPR cost
//  - L1 a1 prefetch between MFMA issue group and silu consumption
// Do NOT widen accumulator state (R9: 208 VGPR -> 2 waves/SIMD -> 2.7x slow).
__global__ __launch_bounds__(64) void edge_kernel(
    const float* __restrict__ node_attr,
    const int*   __restrict__ edge_index,
    const float* __restrict__ edge_attr,
    const float* __restrict__ edge_sh,
    const unsigned short* __restrict__ afrag1,
    const unsigned short* __restrict__ afrag,
    const float* __restrict__ qd,   const float* __restrict__ qvd,
    int* __restrict__ cursor,
    float* __restrict__ exo, float* __restrict__ wout)
{
  __shared__ unsigned char smem[9216];   // per-wave region (1 wave/block)
  const int lane = threadIdx.x;
  const int l15  = lane & 15;
  const int quad = lane >> 4;
  unsigned char* sea = smem;             // 64 x 80 B  (ea hi/lo frags)
  unsigned char* sh  = smem;             // 64 x 144 B (h rows, bf16)
  unsigned char* swp = smem;             // 64 x 144 B (w chunks, f32)

  const int e = blockIdx.x * 64 + lane;
  const bool valid = (e < NE);
  const int el  = valid ? e : (NE - 1);
  const int src = edge_index[el];
  const int dst = edge_index[NE + el];

  int pos = 0;
  if (valid) pos = atomicAdd(&cursor[dst], 1);

  const float s0  = edge_sh[el * 4 + 0];
  const float s1x = edge_sh[el * 4 + 1];
  const float s1y = edge_sh[el * 4 + 2];
  const float s1z = edge_sh[el * 4 + 3];

  // ---- stage ea as bf16 hi + lo (error-compensated) into sea ----
  {
    float ea[16];
    const float4* ea4 = (const float4*)(edge_attr + (size_t)el * 16);
#pragma unroll
    for (int i = 0; i < 4; ++i) {
      float4 v = ea4[i];
      ea[4*i+0] = v.x; ea[4*i+1] = v.y; ea[4*i+2] = v.z; ea[4*i+3] = v.w;
    }
    unsigned char* myrow = sea + lane * 80;
    unsigned hi[8];
    float lo[16];
#pragma unroll
    for (int i = 0; i < 8; ++i) {
      unsigned pk = packbf(ea[2*i], ea[2*i+1]);
      hi[i] = pk;
      lo[2*i]   = ea[2*i]   - bflo(pk);
      lo[2*i+1] = ea[2*i+1] - bfhi(pk);
    }
    uint4 w0 = {hi[0], hi[1], hi[2], hi[3]};
    uint4 w1 = {hi[4], hi[5], hi[6], hi[7]};
    *(uint4*)(myrow)      = w0;
    *(uint4*)(myrow + 16) = w1;
    uint4 w2, w3;
    w2.x = packbf(lo[0], lo[1]);   w2.y = packbf(lo[2], lo[3]);
    w2.z = packbf(lo[4], lo[5]);   w2.w = packbf(lo[6], lo[7]);
    w3.x = packbf(lo[8], lo[9]);   w3.y = packbf(lo[10], lo[11]);
    w3.z = packbf(lo[12], lo[13]); w3.w = packbf(lo[14], lo[15]);
    *(uint4*)(myrow + 32) = w2;
    *(uint4*)(myrow + 48) = w3;
  }

  // ---- B1 fragments (ea) ----
  U16x8 B1[4];
#pragma unroll
  for (int et = 0; et < 4; ++et)
    B1[et].u = *(const uint4*)(sea + (et*16 + l15) * 80 + quad * 16);

  // ---- own-edge node values ----
  float xs[8], xv[8][3];
  {
    const float4* na4 = (const float4*)(node_attr + (size_t)src * 32);
    float tmp[32];
#pragma unroll
    for (int i = 0; i < 8; ++i) {
      float4 v = na4[i];
      tmp[4*i+0] = v.x; tmp[4*i+1] = v.y; tmp[4*i+2] = v.z; tmp[4*i+3] = v.w;
    }
#pragma unroll
    for (int m = 0; m < 8; ++m) xs[m] = tmp[m];
#pragma unroll
    for (int m = 0; m < 8; ++m) {
      xv[m][0] = tmp[8 + 3*m + 0];
      xv[m][1] = tmp[8 + 3*m + 1];
      xv[m][2] = tmp[8 + 3*m + 2];
    }
  }

  const uint4* AF  = (const uint4*)afrag;
  const uint4* AF1 = (const uint4*)afrag1;
  float ex = 0.f;

#pragma unroll 1
  for (int b = 0; b < 2; ++b) {
    // ---- preload chunk-0 A-frags (latency hidden behind the L1 loop) ----
    U16x8 a00, a01, a10, a11;
    {
      const int ci = b * 10;
      a00.u = AF[(ci*4 + 0) * 64 + lane];
      a01.u = AF[(ci*4 + 1) * 64 + lane];
      a10.u = AF[(ci*4 + 2) * 64 + lane];
      a11.u = AF[(ci*4 + 3) * 64 + lane];
    }

    // ---- layer-1: h = silu(ea @ W1 / 4) via 16 MFMA, bf16 h -> sh ----
    U16x8 a1;
    a1.u = AF1[(b * 4 + 0) * 64 + lane];
#pragma unroll 1
    for (int rt = 0; rt < 4; ++rt) {
      f32x4 c[4];
#pragma unroll
      for (int et = 0; et < 4; ++et) {
        f32x4 cz = {0.f, 0.f, 0.f, 0.f};
        c[et] = __builtin_amdgcn_mfma_f32_16x16x32_bf16(a1.v, B1[et].v, cz, 0, 0, 0);
      }
      // prefetch next rt's A1 while the MFMA results drain into silu
      if (rt < 3) a1.u = AF1[(b * 4 + rt + 1) * 64 + lane];
#pragma unroll
      for (int et = 0; et < 4; ++et) {
        float hh[4];
#pragma unroll
        for (int i = 0; i < 4; ++i) {
          float x = c[et][i] * 0.25f;
          hh[i] = x / (1.f + __expf(-x));
        }
        uint2 pk;
        pk.x = packbf(hh[0], hh[1]);
        pk.y = packbf(hh[2], hh[3]);
        *(uint2*)(sh + (et*16 + l15) * 144 + (rt*16 + quad*4) * 2) = pk;
      }
    }

    // ---- B2 fragments (H) ----
    bf16x8 B[4][2];
#pragma unroll
    for (int et = 0; et < 4; ++et) {
#pragma unroll
      for (int kk = 0; kk < 2; ++kk) {
        U16x8 cv;
        cv.u = *(const uint4*)(sh + (et*16 + l15) * 144 + kk * 64 + quad * 16);
        B[et][kk] = cv.v;
      }
    }

    float accs[8];
    float accv[8][3];
#pragma unroll
    for (int n = 0; n < 8; ++n) {
      accs[n] = 0.f;
      accv[n][0] = 0.f; accv[n][1] = 0.f; accv[n][2] = 0.f;
    }

    // ---- 10 chunks, NOT unrolled; A-frags prefetched into dead regs ----
#pragma unroll 1
    for (int cc = 0; cc < 10; ++cc) {
      const int p  = cc >> 1;
      const int hf = cc & 1;

      // C stays f32: row = edge*144, [0,64) = o 0-15, [64,128) = o 16-31
#pragma unroll
      for (int et = 0; et < 4; ++et) {
        f32x4 c0 = {0.f, 0.f, 0.f, 0.f};
        f32x4 c1 = {0.f, 0.f, 0.f, 0.f};
        c0 = __builtin_amdgcn_mfma_f32_16x16x32_bf16(a00.v, B[et][0], c0, 0, 0, 0);
        c0 = __builtin_amdgcn_mfma_f32_16x16x32_bf16(a01.v, B[et][1], c0, 0, 0, 0);
        c1 = __builtin_amdgcn_mfma_f32_16x16x32_bf16(a10.v, B[et][0], c1, 0, 0, 0);
        c1 = __builtin_amdgcn_mfma_f32_16x16x32_bf16(a11.v, B[et][1], c1, 0, 0, 0);
        unsigned char* wrow = swp + (et*16 + l15) * 144;
        *(f32x4*)(wrow + quad * 16)      = c0;   // o = quad*4 + 0..3
        *(f32x4*)(wrow + 64 + quad * 16) = c1;   // o = 16 + quad*4 + 0..3
      }

      const float4* wr = (const float4*)(swp + (size_t)lane * 144);
      // first-half LDS reads issued...
      float4 qa = wr[0], qb = wr[1], qc = wr[2], qd2 = wr[3];
      // ...then next chunk's A-frags into the now-dead a-regs: L2 latency
      // overlaps the contraction below (zero extra registers)
      if (cc < 9) {
        const int cn = b * 10 + cc + 1;
        a00.u = AF[(cn*4 + 0) * 64 + lane];
        a01.u = AF[(cn*4 + 1) * 64 + lane];
        a10.u = AF[(cn*4 + 2) * 64 + lane];
        a11.u = AF[(cn*4 + 3) * 64 + lane];
      }

#pragma unroll
      for (int h2 = 0; h2 < 2; ++h2) {
        float4 ra, rb, rc, rd;
        if (h2 == 0) { ra = qa; rb = qb; rc = qc; rd = qd2; }
        else         { ra = wr[4]; rb = wr[5]; rc = wr[6]; rd = wr[7]; }
        float wvv[16] = {ra.x,ra.y,ra.z,ra.w, rb.x,rb.y,rb.z,rb.w,
                         rc.x,rc.y,rc.z,rc.w, rd.x,rd.y,rd.z,rd.w};
#pragma unroll
        for (int mm = 0; mm < 2; ++mm) {
          const int m = hf * 4 + h2 * 2 + mm;
          const float* wm = &wvv[mm * 8];
          if (p == 0) {
            float g = xs[m] * s0;
#pragma unroll
            for (int n = 0; n < 8; ++n) accs[n] = fmaf(wm[n], g, accs[n]);
          } else if (p == 1) {
            float a = xs[m];
            float gx = a * s1x, gy = a * s1y, gz = a * s1z;
#pragma unroll
            for (int n = 0; n < 8; ++n) {
              accv[n][0] = fmaf(wm[n], gx, accv[n][0]);
              accv[n][1] = fmaf(wm[n], gy, accv[n][1]);
              accv[n][2] = fmaf(wm[n], gz, accv[n][2]);
            }
          } else if (p == 2) {
            float gx = xv[m][0] * s0, gy = xv[m][1] * s0, gz = xv[m][2] * s0;
#pragma unroll
            for (int n = 0; n < 8; ++n) {
              accv[n][0] = fmaf(wm[n], gx, accv[n][0]);
              accv[n][1] = fmaf(wm[n], gy, accv[n][1]);
              accv[n][2] = fmaf(wm[n], gz, accv[n][2]);
            }
          } else if (p == 3) {
            float dm = (xv[m][0]*s1x + xv[m][1]*s1y + xv[m][2]*s1z) * INV_SQRT3;
#pragma unroll
            for (int n = 0; n < 8; ++n) accs[n] = fmaf(wm[n], dm, accs[n]);
          } else {
            float crx = (xv[m][1]*s1z - xv[m][2]*s1y) * INV_SQRT2;
            float cry = (xv[m][2]*s1x - xv[m][0]*s1z) * INV_SQRT2;
            float crz = (xv[m][0]*s1y - xv[m][1]*s1x) * INV_SQRT2;
#pragma unroll
            for (int n = 0; n < 8; ++n) {
              accv[n][0] = fmaf(wm[n], crx, accv[n][0]);
              accv[n][1] = fmaf(wm[n], cry, accv[n][1]);
              accv[n][2] = fmaf(wm[n], crz, accv[n][2]);
            }
          }
        }
      }
    }

    if (b == 0) {
      float lg = 0.f, lv = 0.f;
#pragma unroll
      for (int n = 0; n < 8; ++n) lg = fmaf(accs[n], qd[dst * 8 + n], lg);
#pragma unroll
      for (int n = 0; n < 8; ++n) {
#pragma unroll
        for (int c = 0; c < 3; ++c)
          lv = fmaf(accv[n][c], qvd[dst * 24 + n * 3 + c], lv);
      }
      float logit = (lg * (1.f / 32.f) +
                     lv * (0.125f * INV_SQRT24) * INV_SQRT3) * 0.25f;
      ex = __expf(logit);
      if (valid) exo[pos] = ex;
    } else {
      if (valid) {
        float a = sqrtf(ex);
        const float ss = a * (1.f / 32.f);
        const float sv = a * (0.125f * INV_SQRT24);
        float4* v4 = (float4*)(wout + (size_t)pos * 32);
        float4 o;
        o.x = accs[0] * ss; o.y = accs[1] * ss;
        o.z = accs[2] * ss; o.w = accs[3] * ss;
        v4[0] = o;
        o.x = accs[4] * ss; o.y = accs[5] * ss;
        o.z = accs[6] * ss; o.w = accs[7] * ss;
        v4[1] = o;
        o.x = accv[0][0] * sv; o.y = accv[0][1] * sv;
        o.z = accv[0][2] * sv; o.w = accv[1][0] * sv;
        v4[2] = o;
        o.x = accv[1][1] * sv; o.y = accv[1][2] * sv;
        o.z = accv[2][0] * sv; o.w = accv[2][1] * sv;
        v4[3] = o;
        o.x = accv[2][2] * sv; o.y = accv[3][0] * sv;
        o.z = accv[3][1] * sv; o.w = accv[3][2] * sv;
        v4[4] = o;
        o.x = accv[4][0] * sv; o.y = accv[4][1] * sv;
        o.z = accv[4][2] * sv; o.w = accv[5][0] * sv;
        v4[5] = o;
        o.x = accv[5][1] * sv; o.y = accv[5][2] * sv;
        o.z = accv[6][0] * sv; o.w = accv[6][1] * sv;
        v4[6] = o;
        o.x = accv[6][2] * sv; o.y = accv[7][0] * sv;
        o.z = accv[7][1] * sv; o.w = accv[7][2] * sv;
        v4[7] = o;
      }
    }
  }
}

// ---------------- gather: one wave per node, float4 x 8 rows/iter ----------------
__global__ __launch_bounds__(256) void gather_kernel(
    const int* __restrict__ off,
    const float* __restrict__ exo,
    const float* __restrict__ wout,
    float* __restrict__ out)
{
  const int tid  = threadIdx.x;
  const int wave = tid >> 6;
  const int lane = tid & 63;
  const int n = blockIdx.x * 4 + wave;
  if (n >= NN) return;
  const int start = off[n];
  const int end   = off[n + 1];
  const int cnt   = end - start;

  float zp = 0.f;
  for (int j = start + lane; j < end; j += 64) zp += exo[j];
#pragma unroll
  for (int s = 32; s >= 1; s >>= 1) zp += __shfl_xor(zp, s, 64);

  const int q  = lane & 7;   // float4 column
  const int rr = lane >> 3;  // row within group of 8
  float4 acc = {0.f, 0.f, 0.f, 0.f};
  const float4* w4 = (const float4*)wout;
  for (int j = start + rr; j < end; j += 8) {
    float4 v = w4[(size_t)j * 8 + q];
    acc.x += v.x; acc.y += v.y; acc.z += v.z; acc.w += v.w;
  }
#pragma unroll
  for (int s = 8; s < 64; s <<= 1) {
    acc.x += __shfl_xor(acc.x, s, 64);
    acc.y += __shfl_xor(acc.y, s, 64);
    acc.z += __shfl_xor(acc.z, s, 64);
    acc.w += __shfl_xor(acc.w, s, 64);
  }
  if (rr == 0) {
    float s = (cnt > 0 && zp > 0.f) ? sqrtf((float)cnt / zp) : 0.f;
    float4 o = {acc.x * s, acc.y * s, acc.z * s, acc.w * s};
    ((float4*)out)[(size_t)n * 8 + q] = o;
  }
}

extern "C" void kernel_launch(void* const* d_in, const int* in_sizes, int n_in,
                              void* d_out, int out_size, void* d_ws, size_t ws_size,
                              hipStream_t stream)
{
  const float* node_attr  = (const float*)d_in[0];
  const int*   edge_index = (const int*)  d_in[1];
  const float* edge_attr  = (const float*)d_in[2];
  const float* edge_sh    = (const float*)d_in[3];
  const float* Wq0 = (const float*)d_in[4];
  const float* Wq1 = (const float*)d_in[5];
  const float* kW1 = (const float*)d_in[6];
  const float* kW2 = (const float*)d_in[7];
  const float* vW1 = (const float*)d_in[8];
  const float* vW2 = (const float*)d_in[9];
  const float* Wd0 = (const float*)d_in[10];
  const float* Wd1 = (const float*)d_in[11];
  float* out = (float*)d_out;

  float* ws = (float*)d_ws;
  float* qd     = ws;                    // 200000
  float* qvd    = qd   + 200000;         // 600000
  unsigned short* afrag  = (unsigned short*)(qvd + 600000);   // 40960 ushorts
  unsigned short* afrag1 = afrag + 40960;                     // 4096 ushorts
  int* hist   = (int*)(afrag1 + 4096);                        // 25024 (zero-padded past NN)
  int* off    = hist + 25024;                                 // 25056 (NN+1)
  int* cursor = off  + 25056;                                 // 25024
  float* exo  = (float*)(cursor + 25024);                     // 200000
  float* wout = exo + 200000;                                 // 6400000

  hipMemsetAsync(hist, 0, 25024 * sizeof(int), stream);

  prep_kernel<<<259, 256, 0, stream>>>(
      kW1, kW2, vW1, vW2, node_attr, Wq0, Wq1, Wd0, Wd1, edge_index,
      afrag, afrag1, qd, qvd, hist);
  scan_kernel<<<1, 1024, 0, stream>>>(hist, off, cursor);
  edge_kernel<<<(NE + 63) / 64, 64, 0, stream>>>(
      node_attr, edge_index, edge_attr, edge_sh,
      afrag1, afrag, qd, qvd, cursor, exo, wout);
  gather_kernel<<<(NN + 3) / 4, 256, 0, stream>>>(off, exo, wout, out);
}